// Round 1
// 1333.570 us; speedup vs baseline: 1.5370x; 1.5370x over previous
//
#include <hip/hip_runtime.h>

#define B_  4
#define ROI 90
#define T_  200
#define H_  3
#define F_  96
#define G3  288
#define NSEQ 4           // sequences per stageC workgroup (12 = 3 WGs x 4)
#define TB  8            // timestep batching for global I/O
#define WPAD 104         // padded weight row stride in f16: 208 B = 13*16 B (odd
                         // multiple of 16 B -> ds_read_b128 conflict-free)
#define SMEM_C (576 * WPAD * 2 + 768 + 768 + 1536 + 9216)   // 132096 B

typedef _Float16 f16x2 __attribute__((ext_vector_type(2)));
typedef _Float16 f16x4 __attribute__((ext_vector_type(4)));
typedef _Float16 f16x8 __attribute__((ext_vector_type(8)));

__device__ __forceinline__ float dot2acc(f16x2 a, f16x2 b, float c) {
#if __has_builtin(__builtin_amdgcn_fdot2)
    return __builtin_amdgcn_fdot2(a, b, c, false);
#else
    return c + (float)a.x * (float)b.x + (float)a.y * (float)b.y;
#endif
}

// 8-term dot: u (f16x8, one ds_read_b128) vs 4 f16x2 weight regs.
__device__ __forceinline__ float dot8(f16x8 u, f16x2 w0, f16x2 w1, f16x2 w2,
                                      f16x2 w3, float acc) {
    f16x2 p0 = { u[0], u[1] }, p1 = { u[2], u[3] };
    f16x2 p2 = { u[4], u[5] }, p3 = { u[6], u[7] };
    acc = dot2acc(p0, w0, acc);
    acc = dot2acc(p1, w1, acc);
    acc = dot2acc(p2, w2, acc);
    acc = dot2acc(p3, w3, acc);
    return acc;
}

// 8-term dot where BOTH operands arrive as f16x8 (two ds_read_b128).
__device__ __forceinline__ float dot88(f16x8 u, f16x8 w, float acc) {
    f16x2 ua = { u[0], u[1] }, ub = { u[2], u[3] };
    f16x2 uc = { u[4], u[5] }, ud = { u[6], u[7] };
    f16x2 wa = { w[0], w[1] }, wb = { w[2], w[3] };
    f16x2 wc = { w[4], w[5] }, wd = { w[6], w[7] };
    acc = dot2acc(ua, wa, acc);
    acc = dot2acc(ub, wb, acc);
    acc = dot2acc(uc, wc, acc);
    acc = dot2acc(ud, wd, acc);
    return acc;
}

// ---------------------------------------------------------------------------
// Stage A: per-(b,t,h) block: sparse aggregation + 2-layer MLP (BN+ELU) + relu
// (unchanged from previous round)
// ---------------------------------------------------------------------------
__global__ __launch_bounds__(384, 2) void stageA(
    const float* __restrict__ x, const float* __restrict__ a,
    const float* __restrict__ eps,
    const float* __restrict__ W1, const float* __restrict__ b1,
    const float* __restrict__ g1, const float* __restrict__ be1,
    const float* __restrict__ W2, const float* __restrict__ b2,
    const float* __restrict__ g2, const float* __restrict__ be2,
    float* __restrict__ hbuf)
{
    __shared__ __align__(16) f16x2 xs[ROI][48];   // x tile f16; reused as h1
    __shared__ __align__(16) f16x2 agg[ROI][48];  // aggregated tile f16
    __shared__ __align__(16) f16x2 wbuf[96][49];  // W1 then W2 (transposed, padded)
    __shared__ unsigned char jl[ROI][ROI];        // per-row nonzero col indices
    __shared__ int cnt[ROI];

    const int blk = blockIdx.x;
    const int bb  = blk / (T_ * H_);
    const int rem = blk % (T_ * H_);
    const int t   = rem / H_;
    const int hb  = rem % H_;
    const int tid = threadIdx.x;

    // ---- load x tile (90 x 96 fp32 -> f16 pairs) ----
    for (int idx = tid; idx < ROI * 24; idx += 384) {
        const int j = idx / 24, c4 = idx % 24;
        const float4 v = *(const float4*)(x + ((((long)bb * ROI + j) * T_ + t) * H_ + hb) * F_ + c4 * 4);
        f16x2 p0 = { (_Float16)v.x, (_Float16)v.y };
        f16x2 p1 = { (_Float16)v.z, (_Float16)v.w };
        xs[j][c4 * 2]     = p0;
        xs[j][c4 * 2 + 1] = p1;
    }
    // ---- load W1 transposed+paired ----
    for (int idx = tid; idx < 48 * 96; idx += 384) {
        const int f2 = idx % 96, fp = idx / 96;
        f16x2 p = { (_Float16)W1[(2 * fp) * 96 + f2], (_Float16)W1[(2 * fp + 1) * 96 + f2] };
        wbuf[f2][fp] = p;
    }
    if (tid < ROI) cnt[tid] = 0;
    const float epsv = eps[0];
    __syncthreads();

    // ---- compress adjacency (mask = a != 0 -> exact 1.0 weights -> adds) ----
    for (int idx = tid; idx < ROI * ROI; idx += 384) {
        const int i = idx / ROI, j = idx % ROI;
        const float av = a[((((long)bb * ROI + i) * T_ + t) * H_ + hb) * ROI + j];
        if (av != 0.0f) {
            const int p = atomicAdd(&cnt[i], 1);
            jl[i][p] = (unsigned char)j;
        }
    }
    __syncthreads();

    // ---- agg[i] = sum_{j in list(i)} xs[j] + eps * xs[i] ----
    for (int idx = tid; idx < ROI * 48; idx += 384) {
        const int i = idx / 48, p = idx % 48;
        float s0 = 0.f, s1 = 0.f;
        const int c = cnt[i];
        for (int q = 0; q < c; q++) {
            const f16x2 v = xs[jl[i][q]][p];
            s0 += (float)v.x; s1 += (float)v.y;
        }
        const f16x2 xi = xs[i][p];
        s0 += epsv * (float)xi.x;
        s1 += epsv * (float)xi.y;
        f16x2 o = { (_Float16)s0, (_Float16)s1 };
        agg[i][p] = o;
    }
    __syncthreads();

    const int f2 = tid % 96, isub = tid / 96;   // thread owns output column f2
    f16x2 w[48];
    #pragma unroll
    for (int p = 0; p < 48; p++) w[p] = wbuf[f2][p];
    {
        const float bia = b1[f2];
        const float sc  = g1[f2] * rsqrtf(1.0f + 1e-5f);
        const float sh  = be1[f2];
        _Float16* h1h = (_Float16*)xs;   // xs no longer needed; reuse for h1
        for (int i = isub; i < ROI; i += 4) {
            const f16x8* ar = (const f16x8*)&agg[i][0];
            float acc = 0.f;
            #pragma unroll
            for (int q = 0; q < 12; q++) {
                f16x8 u = ar[q];
                acc = dot8(u, w[4*q], w[4*q+1], w[4*q+2], w[4*q+3], acc);
            }
            float y = (acc + bia) * sc + sh;   // BN (eval mode)
            y = y > 0.f ? y : expm1f(y);       // ELU
            h1h[i * 96 + f2] = (_Float16)y;
        }
    }
    __syncthreads();
    // ---- reload W2 over the same buffer (keeps LDS <= 62 KB) ----
    for (int idx = tid; idx < 48 * 96; idx += 384) {
        const int f2b = idx % 96, fp = idx / 96;
        f16x2 p = { (_Float16)W2[(2 * fp) * 96 + f2b], (_Float16)W2[(2 * fp + 1) * 96 + f2b] };
        wbuf[f2b][fp] = p;
    }
    __syncthreads();
    #pragma unroll
    for (int p = 0; p < 48; p++) w[p] = wbuf[f2][p];
    {
        const float bia = b2[f2];
        const float sc  = g2[f2] * rsqrtf(1.0f + 1e-5f);
        const float sh  = be2[f2];
        for (int i = isub; i < ROI; i += 4) {
            const f16x8* hr = (const f16x8*)&xs[i][0];
            float acc = 0.f;
            #pragma unroll
            for (int q = 0; q < 12; q++) {
                f16x8 u = hr[q];
                acc = dot8(u, w[4*q], w[4*q+1], w[4*q+2], w[4*q+3], acc);
            }
            float y = (acc + bia) * sc + sh;   // BN
            y = fmaxf(y, 0.f);                 // relu(elu(x)) == relu(x)
            hbuf[((((long)bb * ROI + i) * T_ + t) * H_ + hb) * 96 + f2] = y;
        }
    }
}

// ---------------------------------------------------------------------------
// Stage C: GRU. One WG per (roi, third-of-12-sequences): 270 WGs, 576 thr.
// ROUND-0 CHANGE: weight rows now live in LDS (f16, loaded once), NOT in
// VGPRs. Evidence: VGPR_Count=60 < the 48-reg weight column -> the previous
// "register-resident" weights were spilled/rematerialized, injecting per-step
// scratch/L2 reload latency into the 200-step serial recurrence (17.8k
// cyc/step measured vs ~1.5k expected; duration occupancy-invariant).
// LDS layout: row stride 104 f16 = 208 B = 13*16 B -> consecutive lanes'
// ds_read_b128 hit all 8 bank-quads (conflict-free). 132 KB dynamic LDS ->
// 1 WG/CU, which is fine: the kernel is per-WG latency-bound, not
// occupancy-bound (dispatch 0 at occ 4.45% ran the same 1485 us).
// ---------------------------------------------------------------------------
__global__ __launch_bounds__(576, 2) void stageC(
    const float* __restrict__ Wih, const float* __restrict__ Whh,
    const float* __restrict__ bih, const float* __restrict__ bhh,
    float* __restrict__ io)
{
    extern __shared__ __align__(16) char smem[];
    _Float16* wf = (_Float16*)smem;                                  // 576 rows x 104 f16
    f16x8 (*xin)[12]      = (f16x8 (*)[12])(smem + 576 * WPAD * 2);          // + 768 B
    f16x8 (*hcur)[12]     = (f16x8 (*)[12])(smem + 576 * WPAD * 2 + 768);    // + 768 B
    float (*hprev)[96]    = (float (*)[96])(smem + 576 * WPAD * 2 + 1536);   // +1536 B
    float (*gpre)[NSEQ][G3] = (float (*)[NSEQ][G3])(smem + 576 * WPAD * 2 + 3072); // +9216 B

    const int r   = blockIdx.x / 3;
    const int n0  = (blockIdx.x % 3) * NSEQ;
    const int tid = threadIdx.x;
    const int mat = tid / G3;    // 0: Wih, 1: Whh
    const int g   = tid % G3;    // gate row

    // ---- one-time: weights f32 global -> f16 LDS (coalesced, padded rows) ----
    for (int idx = tid; idx < 576 * 24; idx += 576) {
        const int row = idx / 24, c4 = idx % 24;
        const float* src = (row < G3 ? Wih + ((long)r * G3 + row) * 96
                                     : Whh + ((long)r * G3 + (row - G3)) * 96) + c4 * 4;
        const float4 v = *(const float4*)src;
        f16x4 p = { (_Float16)v.x, (_Float16)v.y, (_Float16)v.z, (_Float16)v.w };
        *(f16x4*)(wf + row * WPAD + c4 * 4) = p;
    }
    const float bval = (mat == 0 ? bih : bhh)[(long)r * G3 + g];
    const _Float16* wrow = wf + tid * WPAD;   // this thread's gate row (row == tid)

    const int n  = tid / 96;     // sequence within WG (valid if < NSEQ)
    const int k  = tid % 96;     // hidden index
    const int nn = n0 + (n < NSEQ ? n : 0);
    const int bb = nn / H_, hb = nn % H_;
    float* ioptr = io + ((((long)bb * ROI + r) * T_) * H_ + hb) * 96 + k;
    const bool owns = (n < NSEQ);

    // initial input batch t = 0..TB-1
    float cur[TB];
    #pragma unroll
    for (int j = 0; j < TB; j++) cur[j] = owns ? ioptr[j * (H_ * 96)] : 0.f;

    if (owns) {
        ((_Float16*)hcur)[n * 96 + k] = (_Float16)0.f;
        hprev[n][k] = 0.f;
        ((_Float16*)xin)[n * 96 + k] = (_Float16)cur[0];
    }
    __syncthreads();   // B0: weights + xin/hcur ready for t=0

    for (int tt = 0; tt < T_ / TB; tt++) {
        float nxt[TB], out8[TB];
        #pragma unroll
        for (int j = 0; j < TB; j++) nxt[j] = 0.f;

        for (int j = 0; j < TB; j++) {
            // prefetch next superstep's inputs once; drains at this step's B2
            if (j == 0 && owns && tt + 1 < T_ / TB) {
                #pragma unroll
                for (int p = 0; p < TB; p++)
                    nxt[p] = ioptr[((tt + 1) * TB + p) * (H_ * 96)];
            }

            // gate preactivations: thread (mat,g) for all NSEQ sequences
            const f16x8* src = (mat == 0) ? &xin[0][0] : &hcur[0][0];
            float acc[NSEQ];
            #pragma unroll
            for (int nq = 0; nq < NSEQ; nq++) acc[nq] = bval;
            #pragma unroll
            for (int q = 0; q < 12; q++) {
                const f16x8 wv = *(const f16x8*)(wrow + q * 8);  // conflict-free b128
                f16x8 u0 = src[0 * 12 + q];
                f16x8 u1 = src[1 * 12 + q];
                f16x8 u2 = src[2 * 12 + q];
                f16x8 u3 = src[3 * 12 + q];
                acc[0] = dot88(u0, wv, acc[0]);
                acc[1] = dot88(u1, wv, acc[1]);
                acc[2] = dot88(u2, wv, acc[2]);
                acc[3] = dot88(u3, wv, acc[3]);
            }
            #pragma unroll
            for (int nq = 0; nq < NSEQ; nq++) gpre[mat][nq][g] = acc[nq];
            __syncthreads();                       // B2: gpre ready

            if (owns) {
                const float xr = gpre[0][n][k],       hr = gpre[1][n][k];
                const float xz = gpre[0][n][96 + k],  hz = gpre[1][n][96 + k];
                const float xn = gpre[0][n][192 + k], hn = gpre[1][n][192 + k];
                const float rg = 1.f / (1.f + __expf(-(xr + hr)));
                const float zg = 1.f / (1.f + __expf(-(xz + hz)));
                const float pre = xn + rg * hn;
                const float ng = 1.f - 2.f / (__expf(2.f * pre) + 1.f);  // tanh
                const float hnew = (1.f - zg) * ng + zg * hprev[n][k];
                hprev[n][k] = hnew;
                out8[j] = hnew;
                ((_Float16*)hcur)[n * 96 + k] = (_Float16)hnew;
                // stage NEXT step's input now (input regs already resident)
                ((_Float16*)xin)[n * 96 + k] =
                    (_Float16)(j + 1 < TB ? cur[j + 1] : nxt[0]);
            }
            __syncthreads();                       // B3: xin/hcur ready for t+1
        }

        // batched output write; drains at next superstep's first B2
        if (owns) {
            #pragma unroll
            for (int j = 0; j < TB; j++)
                ioptr[(tt * TB + j) * (H_ * 96)] = out8[j];
        }
        #pragma unroll
        for (int j = 0; j < TB; j++) cur[j] = nxt[j];
    }
}

extern "C" void kernel_launch(void* const* d_in, const int* in_sizes, int n_in,
                              void* d_out, int out_size, void* d_ws, size_t ws_size,
                              hipStream_t stream) {
    (void)in_sizes; (void)n_in; (void)out_size; (void)d_ws; (void)ws_size;
    const float* x   = (const float*)d_in[0];
    const float* a   = (const float*)d_in[1];
    const float* eps = (const float*)d_in[2];
    const float* W1  = (const float*)d_in[3];
    const float* b1  = (const float*)d_in[4];
    const float* g1  = (const float*)d_in[5];
    const float* be1 = (const float*)d_in[6];
    const float* W2  = (const float*)d_in[7];
    const float* b2  = (const float*)d_in[8];
    const float* g2  = (const float*)d_in[9];
    const float* be2 = (const float*)d_in[10];
    const float* Wih = (const float*)d_in[11];
    const float* Whh = (const float*)d_in[12];
    const float* bih = (const float*)d_in[13];
    const float* bhh = (const float*)d_in[14];
    float* out = (float*)d_out;

    stageA<<<B_ * T_ * H_, 384, 0, stream>>>(x, a, eps, W1, b1, g1, be1,
                                             W2, b2, g2, be2, out);
    stageC<<<ROI * 3, 576, SMEM_C, stream>>>(Wih, Whh, bih, bhh, out);
}

// Round 2
// 1146.155 us; speedup vs baseline: 1.7883x; 1.1635x over previous
//
#include <hip/hip_runtime.h>

#define B_  4
#define ROI 90
#define T_  200
#define H_  3
#define F_  96
#define G3  288
#define NSEQ 6           // sequences per stageC workgroup (12 = 2 WGs x 6)
#define TB  8            // timestep batching for global I/O

typedef _Float16 f16x2 __attribute__((ext_vector_type(2)));
typedef _Float16 f16x4 __attribute__((ext_vector_type(4)));
typedef _Float16 f16x8 __attribute__((ext_vector_type(8)));

__device__ __forceinline__ float dot2acc(f16x2 a, f16x2 b, float c) {
#if __has_builtin(__builtin_amdgcn_fdot2)
    return __builtin_amdgcn_fdot2(a, b, c, false);
#else
    return c + (float)a.x * (float)b.x + (float)a.y * (float)b.y;
#endif
}

// 8-term dot: u (f16x8, one ds_read_b128) vs 4 f16x2 weight regs.
__device__ __forceinline__ float dot8(f16x8 u, f16x2 w0, f16x2 w1, f16x2 w2,
                                      f16x2 w3, float acc) {
    f16x2 p0 = { u[0], u[1] }, p1 = { u[2], u[3] };
    f16x2 p2 = { u[4], u[5] }, p3 = { u[6], u[7] };
    acc = dot2acc(p0, w0, acc);
    acc = dot2acc(p1, w1, acc);
    acc = dot2acc(p2, w2, acc);
    acc = dot2acc(p3, w3, acc);
    return acc;
}

// 8-term dot where BOTH operands are f16x8.
__device__ __forceinline__ float dot88(f16x8 u, f16x8 w, float acc) {
    f16x2 ua = { u[0], u[1] }, ub = { u[2], u[3] };
    f16x2 uc = { u[4], u[5] }, ud = { u[6], u[7] };
    f16x2 wa = { w[0], w[1] }, wb = { w[2], w[3] };
    f16x2 wc = { w[4], w[5] }, wd = { w[6], w[7] };
    acc = dot2acc(ua, wa, acc);
    acc = dot2acc(ub, wb, acc);
    acc = dot2acc(uc, wc, acc);
    acc = dot2acc(ud, wd, acc);
    return acc;
}

// ---------------------------------------------------------------------------
// Stage A: per-(b,t,h) block: sparse aggregation + 2-layer MLP (BN+ELU) + relu
// (unchanged this round — its counters will surface in top-5 next round now
// that stageC drops below it, enabling a proper diagnosis)
// ---------------------------------------------------------------------------
__global__ __launch_bounds__(384, 2) void stageA(
    const float* __restrict__ x, const float* __restrict__ a,
    const float* __restrict__ eps,
    const float* __restrict__ W1, const float* __restrict__ b1,
    const float* __restrict__ g1, const float* __restrict__ be1,
    const float* __restrict__ W2, const float* __restrict__ b2,
    const float* __restrict__ g2, const float* __restrict__ be2,
    float* __restrict__ hbuf)
{
    __shared__ __align__(16) f16x2 xs[ROI][48];   // x tile f16; reused as h1
    __shared__ __align__(16) f16x2 agg[ROI][48];  // aggregated tile f16
    __shared__ __align__(16) f16x2 wbuf[96][49];  // W1 then W2 (transposed, padded)
    __shared__ unsigned char jl[ROI][ROI];        // per-row nonzero col indices
    __shared__ int cnt[ROI];

    const int blk = blockIdx.x;
    const int bb  = blk / (T_ * H_);
    const int rem = blk % (T_ * H_);
    const int t   = rem / H_;
    const int hb  = rem % H_;
    const int tid = threadIdx.x;

    // ---- load x tile (90 x 96 fp32 -> f16 pairs) ----
    for (int idx = tid; idx < ROI * 24; idx += 384) {
        const int j = idx / 24, c4 = idx % 24;
        const float4 v = *(const float4*)(x + ((((long)bb * ROI + j) * T_ + t) * H_ + hb) * F_ + c4 * 4);
        f16x2 p0 = { (_Float16)v.x, (_Float16)v.y };
        f16x2 p1 = { (_Float16)v.z, (_Float16)v.w };
        xs[j][c4 * 2]     = p0;
        xs[j][c4 * 2 + 1] = p1;
    }
    // ---- load W1 transposed+paired ----
    for (int idx = tid; idx < 48 * 96; idx += 384) {
        const int f2 = idx % 96, fp = idx / 96;
        f16x2 p = { (_Float16)W1[(2 * fp) * 96 + f2], (_Float16)W1[(2 * fp + 1) * 96 + f2] };
        wbuf[f2][fp] = p;
    }
    if (tid < ROI) cnt[tid] = 0;
    const float epsv = eps[0];
    __syncthreads();

    // ---- compress adjacency (mask = a != 0 -> exact 1.0 weights -> adds) ----
    for (int idx = tid; idx < ROI * ROI; idx += 384) {
        const int i = idx / ROI, j = idx % ROI;
        const float av = a[((((long)bb * ROI + i) * T_ + t) * H_ + hb) * ROI + j];
        if (av != 0.0f) {
            const int p = atomicAdd(&cnt[i], 1);
            jl[i][p] = (unsigned char)j;
        }
    }
    __syncthreads();

    // ---- agg[i] = sum_{j in list(i)} xs[j] + eps * xs[i] ----
    for (int idx = tid; idx < ROI * 48; idx += 384) {
        const int i = idx / 48, p = idx % 48;
        float s0 = 0.f, s1 = 0.f;
        const int c = cnt[i];
        for (int q = 0; q < c; q++) {
            const f16x2 v = xs[jl[i][q]][p];
            s0 += (float)v.x; s1 += (float)v.y;
        }
        const f16x2 xi = xs[i][p];
        s0 += epsv * (float)xi.x;
        s1 += epsv * (float)xi.y;
        f16x2 o = { (_Float16)s0, (_Float16)s1 };
        agg[i][p] = o;
    }
    __syncthreads();

    const int f2 = tid % 96, isub = tid / 96;   // thread owns output column f2
    f16x2 w[48];
    #pragma unroll
    for (int p = 0; p < 48; p++) w[p] = wbuf[f2][p];
    {
        const float bia = b1[f2];
        const float sc  = g1[f2] * rsqrtf(1.0f + 1e-5f);
        const float sh  = be1[f2];
        _Float16* h1h = (_Float16*)xs;   // xs no longer needed; reuse for h1
        for (int i = isub; i < ROI; i += 4) {
            const f16x8* ar = (const f16x8*)&agg[i][0];
            float acc = 0.f;
            #pragma unroll
            for (int q = 0; q < 12; q++) {
                f16x8 u = ar[q];
                acc = dot8(u, w[4*q], w[4*q+1], w[4*q+2], w[4*q+3], acc);
            }
            float y = (acc + bia) * sc + sh;   // BN (eval mode)
            y = y > 0.f ? y : expm1f(y);       // ELU
            h1h[i * 96 + f2] = (_Float16)y;
        }
    }
    __syncthreads();
    // ---- reload W2 over the same buffer (keeps LDS <= 62 KB) ----
    for (int idx = tid; idx < 48 * 96; idx += 384) {
        const int f2b = idx % 96, fp = idx / 96;
        f16x2 p = { (_Float16)W2[(2 * fp) * 96 + f2b], (_Float16)W2[(2 * fp + 1) * 96 + f2b] };
        wbuf[f2b][fp] = p;
    }
    __syncthreads();
    #pragma unroll
    for (int p = 0; p < 48; p++) w[p] = wbuf[f2][p];
    {
        const float bia = b2[f2];
        const float sc  = g2[f2] * rsqrtf(1.0f + 1e-5f);
        const float sh  = be2[f2];
        for (int i = isub; i < ROI; i += 4) {
            const f16x8* hr = (const f16x8*)&xs[i][0];
            float acc = 0.f;
            #pragma unroll
            for (int q = 0; q < 12; q++) {
                f16x8 u = hr[q];
                acc = dot8(u, w[4*q], w[4*q+1], w[4*q+2], w[4*q+3], acc);
            }
            float y = (acc + bia) * sc + sh;   // BN
            y = fmaxf(y, 0.f);                 // relu(elu(x)) == relu(x)
            hbuf[((((long)bb * ROI + i) * T_ + t) * H_ + hb) * 96 + f2] = y;
        }
    }
}

// ---------------------------------------------------------------------------
// Stage C: GRU. ROUND-1 CHANGES:
// (1) Grid 270 -> 180 WGs (NSEQ 4 -> 6): with 1 WG/CU, 270 WGs ran as TWO
//     sequential execution waves (256 + 14) -> total = 2x per-WG latency.
//     Occupancy counter (14.5% = half of the uniform 28%) confirmed this.
//     180 WGs <= 256 CUs -> single wave.
// (2) Weight row back in VGPRs, loaded global->reg ONCE with a FULLY unrolled
//     constant-trip loop (the old failure was '#pragma unroll 4' partial
//     unroll -> no SROA -> scratch; VGPR_Count=60 was the evidence). 12 x
//     f16x8 = 48 VGPRs. Removes 12 ds_read_b128/thread/step (the largest
//     single LDS consumer: 96 cyc/wave/step of the shared LDS pipe).
// (3) LDS shrinks to 18.4 KB static. All 576 threads own a (seq,k) lane in
//     the gate-math phase (6*96 = 576, no idle threads).
// Verification hook: VGPR_Count must rise to ~110-130. If it's ~60 again,
// the register-residency theory is refuted.
// ---------------------------------------------------------------------------
__global__ __launch_bounds__(576, 2) void stageC(
    const float* __restrict__ Wih, const float* __restrict__ Whh,
    const float* __restrict__ bih, const float* __restrict__ bhh,
    float* __restrict__ io)
{
    __shared__ __align__(16) f16x8 xin[NSEQ][12];    // h_in[t] f16      (1152 B)
    __shared__ __align__(16) f16x8 hcur[NSEQ][12];   // recurrent h f16  (1152 B)
    __shared__ float hprev[NSEQ][96];                // recurrent h fp32 (2304 B)
    __shared__ float gpre[2][NSEQ][G3];              // gate preacts    (13824 B)

    const int r   = blockIdx.x >> 1;           // roi
    const int n0  = (blockIdx.x & 1) * NSEQ;   // first sequence of this WG
    const int tid = threadIdx.x;
    const int mat = tid / G3;    // 0: Wih, 1: Whh
    const int g   = tid % G3;    // gate row

    // ---- one-time: this thread's weight row, global f32 -> 12 f16x8 regs ----
    const float* wsrc = (mat == 0 ? Wih : Whh) + ((long)r * G3 + g) * 96;
    f16x8 w[12];
    #pragma unroll
    for (int q = 0; q < 12; q++) {
        const float4 va = *(const float4*)(wsrc + q * 8);
        const float4 vb = *(const float4*)(wsrc + q * 8 + 4);
        f16x8 t = { (_Float16)va.x, (_Float16)va.y, (_Float16)va.z, (_Float16)va.w,
                    (_Float16)vb.x, (_Float16)vb.y, (_Float16)vb.z, (_Float16)vb.w };
        w[q] = t;
    }
    const float bval = (mat == 0 ? bih : bhh)[(long)r * G3 + g];

    const int n  = tid / 96;     // sequence within WG (0..5 — every thread owns)
    const int k  = tid % 96;     // hidden index
    const int nn = n0 + n;
    const int bb = nn / H_, hb = nn % H_;
    float* ioptr = io + ((((long)bb * ROI + r) * T_) * H_ + hb) * 96 + k;

    // initial input batch t = 0..TB-1
    float cur[TB];
    #pragma unroll
    for (int j = 0; j < TB; j++) cur[j] = ioptr[j * (H_ * 96)];

    ((_Float16*)hcur)[n * 96 + k] = (_Float16)0.f;
    hprev[n][k] = 0.f;
    ((_Float16*)xin)[n * 96 + k] = (_Float16)cur[0];
    __syncthreads();   // B0: xin/hcur ready for t=0

    for (int tt = 0; tt < T_ / TB; tt++) {
        float nxt[TB], out8[TB];
        #pragma unroll
        for (int j = 0; j < TB; j++) nxt[j] = 0.f;

        #pragma unroll
        for (int j = 0; j < TB; j++) {
            // prefetch next superstep's inputs once; drains under compute
            if (j == 0 && tt + 1 < T_ / TB) {
                #pragma unroll
                for (int p = 0; p < TB; p++)
                    nxt[p] = ioptr[((tt + 1) * TB + p) * (H_ * 96)];
            }

            // gate preactivations: thread (mat,g) for all NSEQ sequences
            const f16x8* src = (mat == 0) ? &xin[0][0] : &hcur[0][0];
            float acc[NSEQ];
            #pragma unroll
            for (int nq = 0; nq < NSEQ; nq++) acc[nq] = bval;
            #pragma unroll
            for (int q = 0; q < 12; q++) {
                #pragma unroll
                for (int nq = 0; nq < NSEQ; nq++)
                    acc[nq] = dot88(src[nq * 12 + q], w[q], acc[nq]);
            }
            #pragma unroll
            for (int nq = 0; nq < NSEQ; nq++) gpre[mat][nq][g] = acc[nq];
            __syncthreads();                       // B2: gpre ready

            {
                const float xr = gpre[0][n][k],       hr = gpre[1][n][k];
                const float xz = gpre[0][n][96 + k],  hz = gpre[1][n][96 + k];
                const float xn = gpre[0][n][192 + k], hn = gpre[1][n][192 + k];
                const float rg = 1.f / (1.f + __expf(-(xr + hr)));
                const float zg = 1.f / (1.f + __expf(-(xz + hz)));
                const float pre = xn + rg * hn;
                const float ng = 1.f - 2.f / (__expf(2.f * pre) + 1.f);  // tanh
                const float hnew = (1.f - zg) * ng + zg * hprev[n][k];
                hprev[n][k] = hnew;
                out8[j] = hnew;
                ((_Float16*)hcur)[n * 96 + k] = (_Float16)hnew;
                // stage NEXT step's input now (input regs already resident)
                ((_Float16*)xin)[n * 96 + k] =
                    (_Float16)(j + 1 < TB ? cur[j + 1] : nxt[0]);
            }
            __syncthreads();                       // B3: xin/hcur ready for t+1
        }

        // batched output write; drains under next superstep's compute
        #pragma unroll
        for (int j = 0; j < TB; j++)
            ioptr[(tt * TB + j) * (H_ * 96)] = out8[j];
        #pragma unroll
        for (int j = 0; j < TB; j++) cur[j] = nxt[j];
    }
}

extern "C" void kernel_launch(void* const* d_in, const int* in_sizes, int n_in,
                              void* d_out, int out_size, void* d_ws, size_t ws_size,
                              hipStream_t stream) {
    (void)in_sizes; (void)n_in; (void)out_size; (void)d_ws; (void)ws_size;
    const float* x   = (const float*)d_in[0];
    const float* a   = (const float*)d_in[1];
    const float* eps = (const float*)d_in[2];
    const float* W1  = (const float*)d_in[3];
    const float* b1  = (const float*)d_in[4];
    const float* g1  = (const float*)d_in[5];
    const float* be1 = (const float*)d_in[6];
    const float* W2  = (const float*)d_in[7];
    const float* b2  = (const float*)d_in[8];
    const float* g2  = (const float*)d_in[9];
    const float* be2 = (const float*)d_in[10];
    const float* Wih = (const float*)d_in[11];
    const float* Whh = (const float*)d_in[12];
    const float* bih = (const float*)d_in[13];
    const float* bhh = (const float*)d_in[14];
    float* out = (float*)d_out;

    stageA<<<B_ * T_ * H_, 384, 0, stream>>>(x, a, eps, W1, b1, g1, be1,
                                             W2, b2, g2, be2, out);
    stageC<<<ROI * 2, 576, 0, stream>>>(Wih, Whh, bih, bhh, out);
}

// Round 4
// 875.770 us; speedup vs baseline: 2.3404x; 1.3087x over previous
//
#include <hip/hip_runtime.h>

#define B_  4
#define ROI 90
#define T_  200
#define H_  3
#define F_  96
#define G3  288
#define TB  4            // timestep batching for global I/O (stageC)

typedef _Float16 f16x2 __attribute__((ext_vector_type(2)));
typedef _Float16 f16x4 __attribute__((ext_vector_type(4)));
typedef _Float16 f16x8 __attribute__((ext_vector_type(8)));
typedef float    f32x4 __attribute__((ext_vector_type(4)));

__device__ __forceinline__ float dot2acc(f16x2 a, f16x2 b, float c) {
#if __has_builtin(__builtin_amdgcn_fdot2)
    return __builtin_amdgcn_fdot2(a, b, c, false);
#else
    return c + (float)a.x * (float)b.x + (float)a.y * (float)b.y;
#endif
}

// 8-term dot: u (f16x8, one ds_read_b128) vs 4 f16x2 weight regs.
__device__ __forceinline__ float dot8(f16x8 u, f16x2 w0, f16x2 w1, f16x2 w2,
                                      f16x2 w3, float acc) {
    f16x2 p0 = { u[0], u[1] }, p1 = { u[2], u[3] };
    f16x2 p2 = { u[4], u[5] }, p3 = { u[6], u[7] };
    acc = dot2acc(p0, w0, acc);
    acc = dot2acc(p1, w1, acc);
    acc = dot2acc(p2, w2, acc);
    acc = dot2acc(p3, w3, acc);
    return acc;
}

// ---------------------------------------------------------------------------
// Stage A: per-(b,t,h) block: sparse aggregation + 2-layer MLP (BN+ELU) + relu
// (unchanged; passed rounds 0-2)
// ---------------------------------------------------------------------------
__global__ __launch_bounds__(384, 2) void stageA(
    const float* __restrict__ x, const float* __restrict__ a,
    const float* __restrict__ eps,
    const float* __restrict__ W1, const float* __restrict__ b1,
    const float* __restrict__ g1, const float* __restrict__ be1,
    const float* __restrict__ W2, const float* __restrict__ b2,
    const float* __restrict__ g2, const float* __restrict__ be2,
    float* __restrict__ hbuf)
{
    __shared__ __align__(16) f16x2 xs[ROI][48];   // x tile f16; reused as h1
    __shared__ __align__(16) f16x2 agg[ROI][48];  // aggregated tile f16
    __shared__ __align__(16) f16x2 wbuf[96][49];  // W1 then W2 (transposed, padded)
    __shared__ unsigned char jl[ROI][ROI];        // per-row nonzero col indices
    __shared__ int cnt[ROI];

    const int blk = blockIdx.x;
    const int bb  = blk / (T_ * H_);
    const int rem = blk % (T_ * H_);
    const int t   = rem / H_;
    const int hb  = rem % H_;
    const int tid = threadIdx.x;

    for (int idx = tid; idx < ROI * 24; idx += 384) {
        const int j = idx / 24, c4 = idx % 24;
        const float4 v = *(const float4*)(x + ((((long)bb * ROI + j) * T_ + t) * H_ + hb) * F_ + c4 * 4);
        f16x2 p0 = { (_Float16)v.x, (_Float16)v.y };
        f16x2 p1 = { (_Float16)v.z, (_Float16)v.w };
        xs[j][c4 * 2]     = p0;
        xs[j][c4 * 2 + 1] = p1;
    }
    for (int idx = tid; idx < 48 * 96; idx += 384) {
        const int f2 = idx % 96, fp = idx / 96;
        f16x2 p = { (_Float16)W1[(2 * fp) * 96 + f2], (_Float16)W1[(2 * fp + 1) * 96 + f2] };
        wbuf[f2][fp] = p;
    }
    if (tid < ROI) cnt[tid] = 0;
    const float epsv = eps[0];
    __syncthreads();

    for (int idx = tid; idx < ROI * ROI; idx += 384) {
        const int i = idx / ROI, j = idx % ROI;
        const float av = a[((((long)bb * ROI + i) * T_ + t) * H_ + hb) * ROI + j];
        if (av != 0.0f) {
            const int p = atomicAdd(&cnt[i], 1);
            jl[i][p] = (unsigned char)j;
        }
    }
    __syncthreads();

    for (int idx = tid; idx < ROI * 48; idx += 384) {
        const int i = idx / 48, p = idx % 48;
        float s0 = 0.f, s1 = 0.f;
        const int c = cnt[i];
        for (int q = 0; q < c; q++) {
            const f16x2 v = xs[jl[i][q]][p];
            s0 += (float)v.x; s1 += (float)v.y;
        }
        const f16x2 xi = xs[i][p];
        s0 += epsv * (float)xi.x;
        s1 += epsv * (float)xi.y;
        f16x2 o = { (_Float16)s0, (_Float16)s1 };
        agg[i][p] = o;
    }
    __syncthreads();

    const int f2 = tid % 96, isub = tid / 96;
    f16x2 w[48];
    #pragma unroll
    for (int p = 0; p < 48; p++) w[p] = wbuf[f2][p];
    {
        const float bia = b1[f2];
        const float sc  = g1[f2] * rsqrtf(1.0f + 1e-5f);
        const float sh  = be1[f2];
        _Float16* h1h = (_Float16*)xs;
        for (int i = isub; i < ROI; i += 4) {
            const f16x8* ar = (const f16x8*)&agg[i][0];
            float acc = 0.f;
            #pragma unroll
            for (int q = 0; q < 12; q++) {
                f16x8 u = ar[q];
                acc = dot8(u, w[4*q], w[4*q+1], w[4*q+2], w[4*q+3], acc);
            }
            float y = (acc + bia) * sc + sh;
            y = y > 0.f ? y : expm1f(y);
            h1h[i * 96 + f2] = (_Float16)y;
        }
    }
    __syncthreads();
    for (int idx = tid; idx < 48 * 96; idx += 384) {
        const int f2b = idx % 96, fp = idx / 96;
        f16x2 p = { (_Float16)W2[(2 * fp) * 96 + f2b], (_Float16)W2[(2 * fp + 1) * 96 + f2b] };
        wbuf[f2b][fp] = p;
    }
    __syncthreads();
    #pragma unroll
    for (int p = 0; p < 48; p++) w[p] = wbuf[f2][p];
    {
        const float bia = b2[f2];
        const float sc  = g2[f2] * rsqrtf(1.0f + 1e-5f);
        const float sh  = be2[f2];
        for (int i = isub; i < ROI; i += 4) {
            const f16x8* hr = (const f16x8*)&xs[i][0];
            float acc = 0.f;
            #pragma unroll
            for (int q = 0; q < 12; q++) {
                f16x8 u = hr[q];
                acc = dot8(u, w[4*q], w[4*q+1], w[4*q+2], w[4*q+3], acc);
            }
            float y = (acc + bia) * sc + sh;
            y = fmaxf(y, 0.f);
            hbuf[((((long)bb * ROI + i) * T_ + t) * H_ + hb) * 96 + f2] = y;
        }
    }
}

// ---------------------------------------------------------------------------
// Stage C: GRU via MFMA (round-2 design, resubmitted after container-level
// failure; audit found no hang/fault source — see journal).
// One WG per roi (90 WGs, 384 thr = 6 waves); all 12 sequences ride the
// MFMA N dimension. Wave w owns gate rows k in [16w,16w+16) of all
// {r,z,n} x {ih,hh} tiles -> the 6 preactivations for (seq j, hidden k)
// land in one lane's D fragments (D: col=lane&15, row=(lane>>4)*4+reg,
// m89-verified) -> gate nonlinearity fully in-register; no gpre LDS
// round-trip. A/B within-lane K-ordering is permutation-invariant here
// (same pi applies to both operands and cancels in the dot product).
// Per step: 6 ds_read_b128 + 2 ds_write_b64 per lane, 18 MFMA per wave,
// one barrier (double-buffered xact/hact). Weights = 18 resident A-frags
// (72 VGPRs); biases 24 VGPRs; hprev fp32 state in registers.
// launch_bounds(384,1): only 1 WG/CU exists (90 WGs / 256 CUs); do not cap
// the allocator at 256 VGPR and risk spilling the resident fragments.
// ---------------------------------------------------------------------------
__global__ __launch_bounds__(384, 1) void stageC(
    const float* __restrict__ Wih, const float* __restrict__ Whh,
    const float* __restrict__ bih, const float* __restrict__ bhh,
    float* __restrict__ io)
{
    __shared__ __align__(16) _Float16 xact[2][16][104];  // [buf][seq][k] 6656 B
    __shared__ __align__(16) _Float16 hact[2][16][104];  // [buf][seq][k] 6656 B

    const int r    = blockIdx.x;
    const int tid  = threadIdx.x;
    const int w    = tid >> 6;        // wave 0..5
    const int lane = tid & 63;
    const int j    = lane & 15;       // seq (B-frag col / A-frag row / D col)
    const int hi   = lane >> 4;       // quarter-wave
    const int k0   = w * 16 + hi * 4; // this lane's 4 hidden indices k0..k0+3

    // ---- one-time: A-fragments (weights) global f32 -> 18 x f16x8 regs ----
    const float* wb0 = Wih + (long)r * G3 * 96;
    const float* wb1 = Whh + (long)r * G3 * 96;
    f16x8 wf[2][3][3];   // [mat][gate-third][k-tile]
    #pragma unroll
    for (int m = 0; m < 2; m++)
        #pragma unroll
        for (int g = 0; g < 3; g++)
            #pragma unroll
            for (int kt = 0; kt < 3; kt++) {
                const float* src = (m ? wb1 : wb0)
                    + ((long)g * 96 + w * 16 + j) * 96 + kt * 32 + hi * 8;
                const float4 va = *(const float4*)src;
                const float4 vb = *(const float4*)(src + 4);
                f16x8 t = { (_Float16)va.x, (_Float16)va.y, (_Float16)va.z, (_Float16)va.w,
                            (_Float16)vb.x, (_Float16)vb.y, (_Float16)vb.z, (_Float16)vb.w };
                wf[m][g][kt] = t;
            }
    // ---- biases as D-fragment initializers (bias[hidden], uniform over seq) ----
    f32x4 bias[2][3];
    #pragma unroll
    for (int m = 0; m < 2; m++)
        #pragma unroll
        for (int g = 0; g < 3; g++) {
            const float* bsrc = (m ? bhh : bih) + (long)r * G3 + g * 96 + w * 16 + hi * 4;
            f32x4 t = { bsrc[0], bsrc[1], bsrc[2], bsrc[3] };
            bias[m][g] = t;
        }

    const bool owns = (j < 12);
    const int  bb   = (j < 12) ? j / 3 : 0;
    const int  hb   = (j < 12) ? j % 3 : 0;
    float* ioptr = io + ((((long)bb * ROI + r) * T_) * H_ + hb) * 96 + k0;
    const f32x4 zero4 = { 0.f, 0.f, 0.f, 0.f };

    // ---- prologue: first input batch + LDS init ----
    f32x4 cur[TB], nxt[TB];
    #pragma unroll
    for (int jj = 0; jj < TB; jj++)
        cur[jj] = owns ? *(const f32x4*)(ioptr + jj * (H_ * 96)) : zero4;

    {
        f16x4 z4 = { (_Float16)0.f, (_Float16)0.f, (_Float16)0.f, (_Float16)0.f };
        *(f16x4*)&hact[0][j][k0] = z4;
        *(f16x4*)&hact[1][j][k0] = z4;
        *(f16x4*)&xact[1][j][k0] = z4;
        f16x4 x0 = { (_Float16)cur[0][0], (_Float16)cur[0][1],
                     (_Float16)cur[0][2], (_Float16)cur[0][3] };
        *(f16x4*)&xact[0][j][k0] = x0;
    }
    float hprev[4] = { 0.f, 0.f, 0.f, 0.f };
    __syncthreads();   // B0: xact[0]/hact[0] ready for t=0

    for (int tt = 0; tt < T_ / TB; tt++) {
        f32x4 out[TB];
        #pragma unroll
        for (int jj = 0; jj < TB; jj++) {
            if (jj == 0) {
                if (tt + 1 < T_ / TB) {
                    #pragma unroll
                    for (int p = 0; p < TB; p++)
                        nxt[p] = owns ? *(const f32x4*)(ioptr + ((tt + 1) * TB + p) * (H_ * 96))
                                      : zero4;
                } else {
                    #pragma unroll
                    for (int p = 0; p < TB; p++) nxt[p] = zero4;
                }
            }
            const int p = jj & 1;     // read buffer parity (TB even -> p = t&1)

            // ---- MFMA: D = W * [x;h] + bias ----
            f32x4 d[2][3];
            #pragma unroll
            for (int m = 0; m < 2; m++)
                #pragma unroll
                for (int g = 0; g < 3; g++) d[m][g] = bias[m][g];
            #pragma unroll
            for (int kt = 0; kt < 3; kt++) {
                const f16x8 bx = *(const f16x8*)&xact[p][j][kt * 32 + hi * 8];
                const f16x8 bh = *(const f16x8*)&hact[p][j][kt * 32 + hi * 8];
                #pragma unroll
                for (int g = 0; g < 3; g++) {
                    d[0][g] = __builtin_amdgcn_mfma_f32_16x16x32_f16(wf[0][g][kt], bx, d[0][g], 0, 0, 0);
                    d[1][g] = __builtin_amdgcn_mfma_f32_16x16x32_f16(wf[1][g][kt], bh, d[1][g], 0, 0, 0);
                }
            }

            // ---- gate math fully in-register (4 outputs per lane) ----
            f16x4 hq;
            f32x4 ov;
            #pragma unroll
            for (int q = 0; q < 4; q++) {
                const float xr = d[0][0][q], xz = d[0][1][q], xn = d[0][2][q];
                const float hr = d[1][0][q], hz = d[1][1][q], hn = d[1][2][q];
                const float rg = 1.f / (1.f + __expf(-(xr + hr)));
                const float zg = 1.f / (1.f + __expf(-(xz + hz)));
                const float pre = xn + rg * hn;
                const float ng = 1.f - 2.f / (__expf(2.f * pre) + 1.f);  // tanh
                const float hnew = (1.f - zg) * ng + zg * hprev[q];
                hprev[q] = hnew;
                ov[q] = hnew;
                hq[q] = (_Float16)hnew;
            }
            out[jj] = ov;
            *(f16x4*)&hact[1 - p][j][k0] = hq;                 // h_t for step t+1
            const f32x4 xv = (jj + 1 < TB) ? cur[jj + 1] : nxt[0];
            f16x4 xq = { (_Float16)xv[0], (_Float16)xv[1],
                         (_Float16)xv[2], (_Float16)xv[3] };
            *(f16x4*)&xact[1 - p][j][k0] = xq;                 // x_{t+1}
            __syncthreads();   // single barrier/step (double-buffered acts)
        }

        // batched output write (drains at next batch's first barrier)
        if (owns) {
            #pragma unroll
            for (int jj = 0; jj < TB; jj++)
                *(f32x4*)(ioptr + (tt * TB + jj) * (H_ * 96)) = out[jj];
        }
        #pragma unroll
        for (int p = 0; p < TB; p++) cur[p] = nxt[p];
    }
}

extern "C" void kernel_launch(void* const* d_in, const int* in_sizes, int n_in,
                              void* d_out, int out_size, void* d_ws, size_t ws_size,
                              hipStream_t stream) {
    (void)in_sizes; (void)n_in; (void)out_size; (void)d_ws; (void)ws_size;
    const float* x   = (const float*)d_in[0];
    const float* a   = (const float*)d_in[1];
    const float* eps = (const float*)d_in[2];
    const float* W1  = (const float*)d_in[3];
    const float* b1  = (const float*)d_in[4];
    const float* g1  = (const float*)d_in[5];
    const float* be1 = (const float*)d_in[6];
    const float* W2  = (const float*)d_in[7];
    const float* b2  = (const float*)d_in[8];
    const float* g2  = (const float*)d_in[9];
    const float* be2 = (const float*)d_in[10];
    const float* Wih = (const float*)d_in[11];
    const float* Whh = (const float*)d_in[12];
    const float* bih = (const float*)d_in[13];
    const float* bhh = (const float*)d_in[14];
    float* out = (float*)d_out;

    stageA<<<B_ * T_ * H_, 384, 0, stream>>>(x, a, eps, W1, b1, g1, be1,
                                             W2, b2, g2, be2, out);
    stageC<<<ROI, 384, 0, stream>>>(Wih, Whh, bih, bhh, out);
}

// Round 6
// 565.463 us; speedup vs baseline: 3.6248x; 1.5488x over previous
//
#include <hip/hip_runtime.h>

#define B_  4
#define ROI 90
#define T_  200
#define H_  3
#define F_  96
#define G3  288
#define TB  4            // timestep batching for global I/O (stageC)
#define APAD 104         // stageA LDS row stride in f16 (208 B = 13*16 B, b128-conflict-free)
#define ABUF (96 * APAD * 2)          // 19968 B per stageA buffer
#define SMEM_A (4 * ABUF)             // 79872 B dynamic LDS -> 2 WGs/CU

typedef _Float16 f16x4 __attribute__((ext_vector_type(4)));
typedef _Float16 f16x8 __attribute__((ext_vector_type(8)));
typedef float    f32x4 __attribute__((ext_vector_type(4)));

// ---------------------------------------------------------------------------
// Stage A: 3 MFMA GEMMs per (b,t,h) block (round-4 design, resubmitted
// verbatim after container-level failure; full audit found no deadlock /
// fault / race / capacity issue — see journal).
//   agg = mask(90x90) @ x(90x96) [+ eps*x];  h1 = agg @ W1;  h2 = h1 @ W2.
// Fragment layout (HW-verified by round-3 stageC pass):
//   A row = lane&15, k = (lane>>4)*8+e;  B col = lane&15, same k;
//   D col = lane&15 (N), row = (lane>>4)*4+q (M).
// Weights/mask always on the A side (M = out-feature) -> D stores land
// ROW-MAJOR for the next GEMM's B operand; zero inter-GEMM transposes.
// Waves: 6; wave w owns M-strip [16w,16w+16); 6 N-tiles each.
// K pads (j=90..95) zeroed in BOTH operands (NaN containment).
// LDS: 4 dynamic buffers [96][104] f16; 3 barriers total.
// launch_bounds(384,3): 12 waves/CU = 2 WGs/CU; 2x79872 B fits 160 KiB LDS.
// ---------------------------------------------------------------------------
__global__ __launch_bounds__(384, 3) void stageA(
    const float* __restrict__ x, const float* __restrict__ a,
    const float* __restrict__ eps,
    const float* __restrict__ W1, const float* __restrict__ b1,
    const float* __restrict__ g1, const float* __restrict__ be1,
    const float* __restrict__ W2, const float* __restrict__ b2,
    const float* __restrict__ g2, const float* __restrict__ be2,
    float* __restrict__ hbuf)
{
    extern __shared__ __align__(16) char smem[];
    _Float16* xT  = (_Float16*)(smem);             // [96][104] x^T (f,j) -> h1 (i,n)
    _Float16* msk = (_Float16*)(smem + ABUF);      // [96][104] mask (i,j) -> w2T (f,n)
    _Float16* w1T = (_Float16*)(smem + 2 * ABUF);  // [96][104] W1^T (n,f)
    _Float16* agg = (_Float16*)(smem + 3 * ABUF);  // [96][104] agg (i,f)

    const int blk = blockIdx.x;
    const int bb  = blk / (T_ * H_);
    const int rem = blk % (T_ * H_);
    const int t   = rem / H_;
    const int hb  = rem % H_;
    const int tid = threadIdx.x;
    const int w    = tid >> 6;       // wave 0..5 = M-strip
    const int lane = tid & 63;
    const int l15  = lane & 15;
    const int hig  = lane >> 4;

    const float epsv = eps[0];

    // ---- zero K-pad strips (disjoint from data writes -> no extra barrier) ----
    for (int idx = tid; idx < 1692; idx += 384) {
        if (idx < 576) {                       // xT[f][90..96), f in [0,96)
            const int f = idx / 6, c = idx % 6;
            xT[f * APAD + 90 + c] = (_Float16)0.f;
        } else if (idx < 1116) {               // msk[i][90..96), i in [0,90)
            const int k = idx - 576; const int i = k / 6, c = k % 6;
            msk[i * APAD + 90 + c] = (_Float16)0.f;
        } else {                               // msk[90..96)[0..96)
            const int k = idx - 1116; const int i = 90 + k / 96, c = k % 96;
            msk[i * APAD + c] = (_Float16)0.f;
        }
    }
    // ---- build x^T tile (coalesced float4 read, transposed f16 write) ----
    for (int idx = tid; idx < ROI * 24; idx += 384) {
        const int j = idx / 24, c4 = idx % 24;
        const float4 v = *(const float4*)(x + ((((long)bb * ROI + j) * T_ + t) * H_ + hb) * F_ + c4 * 4);
        xT[(c4 * 4 + 0) * APAD + j] = (_Float16)v.x;
        xT[(c4 * 4 + 1) * APAD + j] = (_Float16)v.y;
        xT[(c4 * 4 + 2) * APAD + j] = (_Float16)v.z;
        xT[(c4 * 4 + 3) * APAD + j] = (_Float16)v.w;
    }
    // ---- build mask tile directly (no compress/gather) ----
    for (int idx = tid; idx < ROI * ROI; idx += 384) {
        const int i = idx / ROI, j = idx % ROI;
        const float av = a[((((long)bb * ROI + i) * T_ + t) * H_ + hb) * ROI + j];
        msk[i * APAD + j] = (_Float16)(av != 0.0f ? 1.0f : 0.0f);
    }
    // ---- W1^T (coalesced read along n, scattered f16 write) ----
    for (int idx = tid; idx < 96 * 96; idx += 384) {
        const int f = idx / 96, n = idx % 96;
        w1T[n * APAD + f] = (_Float16)W1[f * 96 + n];
    }
    __syncthreads();   // B1: tiles ready

    // ================= GEMM1: agg(i,f) = mask @ x (+ eps*x) =================
    // A = xT (M=f, K=j), B = msk (N=i, K=j), D: col=i, row=f
    {
        f16x8 a1[3];
        #pragma unroll
        for (int kt = 0; kt < 3; kt++)
            a1[kt] = *(const f16x8*)&xT[(w * 16 + l15) * APAD + kt * 32 + hig * 8];
        const int f0 = w * 16 + hig * 4;
        #pragma unroll
        for (int nt = 0; nt < 6; nt++) {
            f32x4 d = { 0.f, 0.f, 0.f, 0.f };
            #pragma unroll
            for (int kt = 0; kt < 3; kt++) {
                const f16x8 b = *(const f16x8*)&msk[(nt * 16 + l15) * APAD + kt * 32 + hig * 8];
                d = __builtin_amdgcn_mfma_f32_16x16x32_f16(a1[kt], b, d, 0, 0, 0);
            }
            const int i = nt * 16 + l15;
            f16x4 o;
            #pragma unroll
            for (int q = 0; q < 4; q++)
                o[q] = (_Float16)(d[q] + epsv * (float)xT[(f0 + q) * APAD + i]);
            *(f16x4*)&agg[i * APAD + f0] = o;
        }
    }
    __syncthreads();   // B2: agg ready; xT & msk now dead

    // ---- load W2^T into msk's slot (concurrent with GEMM2 - disjoint bufs) ----
    for (int idx = tid; idx < 96 * 96; idx += 384) {
        const int n = idx / 96, f = idx % 96;
        msk[f * APAD + n] = (_Float16)W2[n * 96 + f];
    }
    // ================= GEMM2: h1(i,n) = ELU(BN(agg @ W1)) =================
    // A = w1T (M=n, K=f), B = agg (N=i, K=f), D: col=i, row=n -> h1 into xT slot
    {
        f16x8 a2[3];
        #pragma unroll
        for (int kt = 0; kt < 3; kt++)
            a2[kt] = *(const f16x8*)&w1T[(w * 16 + l15) * APAD + kt * 32 + hig * 8];
        const int n0 = w * 16 + hig * 4;
        const float4 bv = *(const float4*)(b1 + n0);
        const float4 gv = *(const float4*)(g1 + n0);
        const float4 ev = *(const float4*)(be1 + n0);
        const float rs = rsqrtf(1.0f + 1e-5f);
        #pragma unroll
        for (int nt = 0; nt < 6; nt++) {
            f32x4 d = { 0.f, 0.f, 0.f, 0.f };
            #pragma unroll
            for (int kt = 0; kt < 3; kt++) {
                const f16x8 b = *(const f16x8*)&agg[(nt * 16 + l15) * APAD + kt * 32 + hig * 8];
                d = __builtin_amdgcn_mfma_f32_16x16x32_f16(a2[kt], b, d, 0, 0, 0);
            }
            const int i = nt * 16 + l15;
            f16x4 o;
            #pragma unroll
            for (int q = 0; q < 4; q++) {
                float y = (d[q] + ((const float*)&bv)[q]) * (((const float*)&gv)[q] * rs)
                          + ((const float*)&ev)[q];
                y = y > 0.f ? y : expm1f(y);    // ELU
                o[q] = (_Float16)y;
            }
            *(f16x4*)&xT[i * APAD + n0] = o;    // h1 row-major (i,n)
        }
    }
    __syncthreads();   // B3: h1 + w2T ready

    // ================= GEMM3: out(i,f) = relu(BN(h1 @ W2)) =================
    // A = w2T (M=f, K=n), B = h1 (N=i, K=n), D: col=i, row=f -> global float4
    {
        f16x8 a3[3];
        #pragma unroll
        for (int kt = 0; kt < 3; kt++)
            a3[kt] = *(const f16x8*)&msk[(w * 16 + l15) * APAD + kt * 32 + hig * 8];
        const int f0 = w * 16 + hig * 4;
        const float4 bv = *(const float4*)(b2 + f0);
        const float4 gv = *(const float4*)(g2 + f0);
        const float4 ev = *(const float4*)(be2 + f0);
        const float rs = rsqrtf(1.0f + 1e-5f);
        #pragma unroll
        for (int nt = 0; nt < 6; nt++) {
            f32x4 d = { 0.f, 0.f, 0.f, 0.f };
            #pragma unroll
            for (int kt = 0; kt < 3; kt++) {
                const f16x8 b = *(const f16x8*)&xT[(nt * 16 + l15) * APAD + kt * 32 + hig * 8];
                d = __builtin_amdgcn_mfma_f32_16x16x32_f16(a3[kt], b, d, 0, 0, 0);
            }
            const int i = nt * 16 + l15;
            if (i < ROI) {
                float4 o;
                #pragma unroll
                for (int q = 0; q < 4; q++) {
                    float y = (d[q] + ((const float*)&bv)[q]) * (((const float*)&gv)[q] * rs)
                              + ((const float*)&ev)[q];
                    ((float*)&o)[q] = fmaxf(y, 0.f);   // relu(elu(x)) == relu(x)
                }
                *(float4*)(hbuf + ((((long)bb * ROI + i) * T_ + t) * H_ + hb) * 96 + f0) = o;
            }
        }
    }
}

// ---------------------------------------------------------------------------
// Stage C: GRU via MFMA (unchanged from round 3 — passed at ~407 us).
// ---------------------------------------------------------------------------
__global__ __launch_bounds__(384, 1) void stageC(
    const float* __restrict__ Wih, const float* __restrict__ Whh,
    const float* __restrict__ bih, const float* __restrict__ bhh,
    float* __restrict__ io)
{
    __shared__ __align__(16) _Float16 xact[2][16][104];  // [buf][seq][k] 6656 B
    __shared__ __align__(16) _Float16 hact[2][16][104];  // [buf][seq][k] 6656 B

    const int r    = blockIdx.x;
    const int tid  = threadIdx.x;
    const int w    = tid >> 6;        // wave 0..5
    const int lane = tid & 63;
    const int j    = lane & 15;       // seq (B-frag col / A-frag row / D col)
    const int hi   = lane >> 4;       // quarter-wave
    const int k0   = w * 16 + hi * 4; // this lane's 4 hidden indices k0..k0+3

    const float* wb0 = Wih + (long)r * G3 * 96;
    const float* wb1 = Whh + (long)r * G3 * 96;
    f16x8 wf[2][3][3];   // [mat][gate-third][k-tile]
    #pragma unroll
    for (int m = 0; m < 2; m++)
        #pragma unroll
        for (int g = 0; g < 3; g++)
            #pragma unroll
            for (int kt = 0; kt < 3; kt++) {
                const float* src = (m ? wb1 : wb0)
                    + ((long)g * 96 + w * 16 + j) * 96 + kt * 32 + hi * 8;
                const float4 va = *(const float4*)src;
                const float4 vb = *(const float4*)(src + 4);
                f16x8 t = { (_Float16)va.x, (_Float16)va.y, (_Float16)va.z, (_Float16)va.w,
                            (_Float16)vb.x, (_Float16)vb.y, (_Float16)vb.z, (_Float16)vb.w };
                wf[m][g][kt] = t;
            }
    f32x4 bias[2][3];
    #pragma unroll
    for (int m = 0; m < 2; m++)
        #pragma unroll
        for (int g = 0; g < 3; g++) {
            const float* bsrc = (m ? bhh : bih) + (long)r * G3 + g * 96 + w * 16 + hi * 4;
            f32x4 t = { bsrc[0], bsrc[1], bsrc[2], bsrc[3] };
            bias[m][g] = t;
        }

    const bool owns = (j < 12);
    const int  bb   = (j < 12) ? j / 3 : 0;
    const int  hb   = (j < 12) ? j % 3 : 0;
    float* ioptr = io + ((((long)bb * ROI + r) * T_) * H_ + hb) * 96 + k0;
    const f32x4 zero4 = { 0.f, 0.f, 0.f, 0.f };

    f32x4 cur[TB], nxt[TB];
    #pragma unroll
    for (int jj = 0; jj < TB; jj++)
        cur[jj] = owns ? *(const f32x4*)(ioptr + jj * (H_ * 96)) : zero4;

    {
        f16x4 z4 = { (_Float16)0.f, (_Float16)0.f, (_Float16)0.f, (_Float16)0.f };
        *(f16x4*)&hact[0][j][k0] = z4;
        *(f16x4*)&hact[1][j][k0] = z4;
        *(f16x4*)&xact[1][j][k0] = z4;
        f16x4 x0 = { (_Float16)cur[0][0], (_Float16)cur[0][1],
                     (_Float16)cur[0][2], (_Float16)cur[0][3] };
        *(f16x4*)&xact[0][j][k0] = x0;
    }
    float hprev[4] = { 0.f, 0.f, 0.f, 0.f };
    __syncthreads();   // B0: xact[0]/hact[0] ready for t=0

    for (int tt = 0; tt < T_ / TB; tt++) {
        f32x4 out[TB];
        #pragma unroll
        for (int jj = 0; jj < TB; jj++) {
            if (jj == 0) {
                if (tt + 1 < T_ / TB) {
                    #pragma unroll
                    for (int p = 0; p < TB; p++)
                        nxt[p] = owns ? *(const f32x4*)(ioptr + ((tt + 1) * TB + p) * (H_ * 96))
                                      : zero4;
                } else {
                    #pragma unroll
                    for (int p = 0; p < TB; p++) nxt[p] = zero4;
                }
            }
            const int p = jj & 1;     // read buffer parity (TB even -> p = t&1)

            f32x4 d[2][3];
            #pragma unroll
            for (int m = 0; m < 2; m++)
                #pragma unroll
                for (int g = 0; g < 3; g++) d[m][g] = bias[m][g];
            #pragma unroll
            for (int kt = 0; kt < 3; kt++) {
                const f16x8 bx = *(const f16x8*)&xact[p][j][kt * 32 + hi * 8];
                const f16x8 bh = *(const f16x8*)&hact[p][j][kt * 32 + hi * 8];
                #pragma unroll
                for (int g = 0; g < 3; g++) {
                    d[0][g] = __builtin_amdgcn_mfma_f32_16x16x32_f16(wf[0][g][kt], bx, d[0][g], 0, 0, 0);
                    d[1][g] = __builtin_amdgcn_mfma_f32_16x16x32_f16(wf[1][g][kt], bh, d[1][g], 0, 0, 0);
                }
            }

            f16x4 hq;
            f32x4 ov;
            #pragma unroll
            for (int q = 0; q < 4; q++) {
                const float xr = d[0][0][q], xz = d[0][1][q], xn = d[0][2][q];
                const float hr = d[1][0][q], hz = d[1][1][q], hn = d[1][2][q];
                const float rg = 1.f / (1.f + __expf(-(xr + hr)));
                const float zg = 1.f / (1.f + __expf(-(xz + hz)));
                const float pre = xn + rg * hn;
                const float ng = 1.f - 2.f / (__expf(2.f * pre) + 1.f);  // tanh
                const float hnew = (1.f - zg) * ng + zg * hprev[q];
                hprev[q] = hnew;
                ov[q] = hnew;
                hq[q] = (_Float16)hnew;
            }
            out[jj] = ov;
            *(f16x4*)&hact[1 - p][j][k0] = hq;                 // h_t for step t+1
            const f32x4 xv = (jj + 1 < TB) ? cur[jj + 1] : nxt[0];
            f16x4 xq = { (_Float16)xv[0], (_Float16)xv[1],
                         (_Float16)xv[2], (_Float16)xv[3] };
            *(f16x4*)&xact[1 - p][j][k0] = xq;                 // x_{t+1}
            __syncthreads();   // single barrier/step (double-buffered acts)
        }

        if (owns) {
            #pragma unroll
            for (int jj = 0; jj < TB; jj++)
                *(f32x4*)(ioptr + (tt * TB + jj) * (H_ * 96)) = out[jj];
        }
        #pragma unroll
        for (int p = 0; p < TB; p++) cur[p] = nxt[p];
    }
}

extern "C" void kernel_launch(void* const* d_in, const int* in_sizes, int n_in,
                              void* d_out, int out_size, void* d_ws, size_t ws_size,
                              hipStream_t stream) {
    (void)in_sizes; (void)n_in; (void)out_size; (void)d_ws; (void)ws_size;
    const float* x   = (const float*)d_in[0];
    const float* a   = (const float*)d_in[1];
    const float* eps = (const float*)d_in[2];
    const float* W1  = (const float*)d_in[3];
    const float* b1  = (const float*)d_in[4];
    const float* g1  = (const float*)d_in[5];
    const float* be1 = (const float*)d_in[6];
    const float* W2  = (const float*)d_in[7];
    const float* b2  = (const float*)d_in[8];
    const float* g2  = (const float*)d_in[9];
    const float* be2 = (const float*)d_in[10];
    const float* Wih = (const float*)d_in[11];
    const float* Whh = (const float*)d_in[12];
    const float* bih = (const float*)d_in[13];
    const float* bhh = (const float*)d_in[14];
    float* out = (float*)d_out;

    stageA<<<B_ * T_ * H_, 384, SMEM_A, stream>>>(x, a, eps, W1, b1, g1, be1,
                                                  W2, b2, g2, be2, out);
    stageC<<<ROI, 384, 0, stream>>>(Wih, Whh, bih, bhh, out);
}

// Round 7
// 524.696 us; speedup vs baseline: 3.9064x; 1.0777x over previous
//
#include <hip/hip_runtime.h>

#define B_  4
#define ROI 90
#define T_  200
#define H_  3
#define F_  96
#define G3  288
#define TB  4            // timestep batching for global I/O (stageC)
#define APAD 104         // stageA LDS row stride in f16 (208 B = 13*16 B, b128-conflict-free)
#define ABUF (96 * APAD * 2)          // 19968 B per stageA buffer
#define SMEM_A (4 * ABUF)             // 79872 B dynamic LDS -> 2 WGs/CU

typedef _Float16 f16x4 __attribute__((ext_vector_type(4)));
typedef _Float16 f16x8 __attribute__((ext_vector_type(8)));
typedef float    f32x4 __attribute__((ext_vector_type(4)));

// Raw barrier: lgkmcnt-only wait, NO vmcnt drain (unlike __syncthreads, whose
// implicit s_waitcnt vmcnt(0) injected HBM prefetch/store latency into every
// step of the recurrence). asm memory clobbers fence the compiler on both
// sides; s_barrier orders the waves on HW (m201-template pattern).
#define BAR() do {                                            \
    asm volatile("s_waitcnt lgkmcnt(0)" ::: "memory");        \
    __builtin_amdgcn_s_barrier();                             \
    asm volatile("" ::: "memory");                            \
} while (0)

// ---------------------------------------------------------------------------
// Stage A: 3 MFMA GEMMs per (b,t,h) block (round-4 design — unchanged; it is
// now ~275 us and becomes the optimization target next round).
// ---------------------------------------------------------------------------
__global__ __launch_bounds__(384, 3) void stageA(
    const float* __restrict__ x, const float* __restrict__ a,
    const float* __restrict__ eps,
    const float* __restrict__ W1, const float* __restrict__ b1,
    const float* __restrict__ g1, const float* __restrict__ be1,
    const float* __restrict__ W2, const float* __restrict__ b2,
    const float* __restrict__ g2, const float* __restrict__ be2,
    float* __restrict__ hbuf)
{
    extern __shared__ __align__(16) char smem[];
    _Float16* xT  = (_Float16*)(smem);             // [96][104] x^T (f,j) -> h1 (i,n)
    _Float16* msk = (_Float16*)(smem + ABUF);      // [96][104] mask (i,j) -> w2T (f,n)
    _Float16* w1T = (_Float16*)(smem + 2 * ABUF);  // [96][104] W1^T (n,f)
    _Float16* agg = (_Float16*)(smem + 3 * ABUF);  // [96][104] agg (i,f)

    const int blk = blockIdx.x;
    const int bb  = blk / (T_ * H_);
    const int rem = blk % (T_ * H_);
    const int t   = rem / H_;
    const int hb  = rem % H_;
    const int tid = threadIdx.x;
    const int w    = tid >> 6;       // wave 0..5 = M-strip
    const int lane = tid & 63;
    const int l15  = lane & 15;
    const int hig  = lane >> 4;

    const float epsv = eps[0];

    // ---- zero K-pad strips ----
    for (int idx = tid; idx < 1692; idx += 384) {
        if (idx < 576) {
            const int f = idx / 6, c = idx % 6;
            xT[f * APAD + 90 + c] = (_Float16)0.f;
        } else if (idx < 1116) {
            const int k = idx - 576; const int i = k / 6, c = k % 6;
            msk[i * APAD + 90 + c] = (_Float16)0.f;
        } else {
            const int k = idx - 1116; const int i = 90 + k / 96, c = k % 96;
            msk[i * APAD + c] = (_Float16)0.f;
        }
    }
    // ---- build x^T tile ----
    for (int idx = tid; idx < ROI * 24; idx += 384) {
        const int j = idx / 24, c4 = idx % 24;
        const float4 v = *(const float4*)(x + ((((long)bb * ROI + j) * T_ + t) * H_ + hb) * F_ + c4 * 4);
        xT[(c4 * 4 + 0) * APAD + j] = (_Float16)v.x;
        xT[(c4 * 4 + 1) * APAD + j] = (_Float16)v.y;
        xT[(c4 * 4 + 2) * APAD + j] = (_Float16)v.z;
        xT[(c4 * 4 + 3) * APAD + j] = (_Float16)v.w;
    }
    // ---- build mask tile ----
    for (int idx = tid; idx < ROI * ROI; idx += 384) {
        const int i = idx / ROI, j = idx % ROI;
        const float av = a[((((long)bb * ROI + i) * T_ + t) * H_ + hb) * ROI + j];
        msk[i * APAD + j] = (_Float16)(av != 0.0f ? 1.0f : 0.0f);
    }
    // ---- W1^T ----
    for (int idx = tid; idx < 96 * 96; idx += 384) {
        const int f = idx / 96, n = idx % 96;
        w1T[n * APAD + f] = (_Float16)W1[f * 96 + n];
    }
    __syncthreads();   // B1: tiles ready

    // ================= GEMM1: agg(i,f) = mask @ x (+ eps*x) =================
    {
        f16x8 a1[3];
        #pragma unroll
        for (int kt = 0; kt < 3; kt++)
            a1[kt] = *(const f16x8*)&xT[(w * 16 + l15) * APAD + kt * 32 + hig * 8];
        const int f0 = w * 16 + hig * 4;
        #pragma unroll
        for (int nt = 0; nt < 6; nt++) {
            f32x4 d = { 0.f, 0.f, 0.f, 0.f };
            #pragma unroll
            for (int kt = 0; kt < 3; kt++) {
                const f16x8 b = *(const f16x8*)&msk[(nt * 16 + l15) * APAD + kt * 32 + hig * 8];
                d = __builtin_amdgcn_mfma_f32_16x16x32_f16(a1[kt], b, d, 0, 0, 0);
            }
            const int i = nt * 16 + l15;
            f16x4 o;
            #pragma unroll
            for (int q = 0; q < 4; q++)
                o[q] = (_Float16)(d[q] + epsv * (float)xT[(f0 + q) * APAD + i]);
            *(f16x4*)&agg[i * APAD + f0] = o;
        }
    }
    __syncthreads();   // B2: agg ready; xT & msk now dead

    // ---- load W2^T into msk's slot ----
    for (int idx = tid; idx < 96 * 96; idx += 384) {
        const int n = idx / 96, f = idx % 96;
        msk[f * APAD + n] = (_Float16)W2[n * 96 + f];
    }
    // ================= GEMM2: h1(i,n) = ELU(BN(agg @ W1)) =================
    {
        f16x8 a2[3];
        #pragma unroll
        for (int kt = 0; kt < 3; kt++)
            a2[kt] = *(const f16x8*)&w1T[(w * 16 + l15) * APAD + kt * 32 + hig * 8];
        const int n0 = w * 16 + hig * 4;
        const float4 bv = *(const float4*)(b1 + n0);
        const float4 gv = *(const float4*)(g1 + n0);
        const float4 ev = *(const float4*)(be1 + n0);
        const float rs = rsqrtf(1.0f + 1e-5f);
        #pragma unroll
        for (int nt = 0; nt < 6; nt++) {
            f32x4 d = { 0.f, 0.f, 0.f, 0.f };
            #pragma unroll
            for (int kt = 0; kt < 3; kt++) {
                const f16x8 b = *(const f16x8*)&agg[(nt * 16 + l15) * APAD + kt * 32 + hig * 8];
                d = __builtin_amdgcn_mfma_f32_16x16x32_f16(a2[kt], b, d, 0, 0, 0);
            }
            const int i = nt * 16 + l15;
            f16x4 o;
            #pragma unroll
            for (int q = 0; q < 4; q++) {
                float y = (d[q] + ((const float*)&bv)[q]) * (((const float*)&gv)[q] * rs)
                          + ((const float*)&ev)[q];
                y = y > 0.f ? y : expm1f(y);    // ELU
                o[q] = (_Float16)y;
            }
            *(f16x4*)&xT[i * APAD + n0] = o;    // h1 row-major (i,n)
        }
    }
    __syncthreads();   // B3: h1 + w2T ready

    // ================= GEMM3: out(i,f) = relu(BN(h1 @ W2)) =================
    {
        f16x8 a3[3];
        #pragma unroll
        for (int kt = 0; kt < 3; kt++)
            a3[kt] = *(const f16x8*)&msk[(w * 16 + l15) * APAD + kt * 32 + hig * 8];
        const int f0 = w * 16 + hig * 4;
        const float4 bv = *(const float4*)(b2 + f0);
        const float4 gv = *(const float4*)(g2 + f0);
        const float4 ev = *(const float4*)(be2 + f0);
        const float rs = rsqrtf(1.0f + 1e-5f);
        #pragma unroll
        for (int nt = 0; nt < 6; nt++) {
            f32x4 d = { 0.f, 0.f, 0.f, 0.f };
            #pragma unroll
            for (int kt = 0; kt < 3; kt++) {
                const f16x8 b = *(const f16x8*)&xT[(nt * 16 + l15) * APAD + kt * 32 + hig * 8];
                d = __builtin_amdgcn_mfma_f32_16x16x32_f16(a3[kt], b, d, 0, 0, 0);
            }
            const int i = nt * 16 + l15;
            if (i < ROI) {
                float4 o;
                #pragma unroll
                for (int q = 0; q < 4; q++) {
                    float y = (d[q] + ((const float*)&bv)[q]) * (((const float*)&gv)[q] * rs)
                              + ((const float*)&ev)[q];
                    ((float*)&o)[q] = fmaxf(y, 0.f);
                }
                *(float4*)(hbuf + ((((long)bb * ROI + i) * T_ + t) * H_ + hb) * 96 + f0) = o;
            }
        }
    }
}

// ---------------------------------------------------------------------------
// Stage C: GRU via MFMA. ROUND-6 CHANGES (diagnosed from r5 counters:
// 3325 cyc/step vs ~800 issue-work -> serial-chain stall):
// (1) Raw lgkmcnt-only barriers (BAR): __syncthreads' implicit vmcnt(0)
//     drained the nxt-prefetch + output stores INSIDE every step. Now
//     global I/O stays in flight across barriers; stores fire per-step.
// (2) x-side decoupled from the recurrence: step t computes xpre(t+1) =
//     bih + Wih@x[t+1] as independent MFMA work; gate math consumes
//     xpre(t) from REGISTERS (computed last step). Critical chain is now
//     only: 3 ds_read -> 9 MFMA (3 parallel 3-deep chains) -> gates ->
//     1 ds_write -> barrier. Bit-identical arithmetic (same MFMAs/order).
// xpre state in two NAMED f32x4[3] sets alternated by static jj-parity
// (rule 20: no runtime-indexed register arrays).
// launch_bounds(384,2) is REQUIRED: 6-wave WG puts 2 waves on two SIMDs
// -> VGPR must be <=256 or the WG cannot launch. Est ~196 VGPR.
// ---------------------------------------------------------------------------
__global__ __launch_bounds__(384, 2) void stageC(
    const float* __restrict__ Wih, const float* __restrict__ Whh,
    const float* __restrict__ bih, const float* __restrict__ bhh,
    float* __restrict__ io)
{
    __shared__ __align__(16) _Float16 xact[2][16][104];  // x[t] staged, parity t&1
    __shared__ __align__(16) _Float16 hact[2][16][104];  // h[t] staged, parity t&1

    const int r    = blockIdx.x;
    const int tid  = threadIdx.x;
    const int w    = tid >> 6;        // wave 0..5
    const int lane = tid & 63;
    const int j    = lane & 15;       // seq (B-frag col / A-frag row / D col)
    const int hi   = lane >> 4;       // quarter-wave
    const int k0   = w * 16 + hi * 4; // this lane's 4 hidden indices

    // ---- one-time: A-fragments (weights) global f32 -> 18 x f16x8 regs ----
    const float* wb0 = Wih + (long)r * G3 * 96;
    const float* wb1 = Whh + (long)r * G3 * 96;
    f16x8 wf[2][3][3];   // [mat][gate][k-tile]
    #pragma unroll
    for (int m = 0; m < 2; m++)
        #pragma unroll
        for (int g = 0; g < 3; g++)
            #pragma unroll
            for (int kt = 0; kt < 3; kt++) {
                const float* src = (m ? wb1 : wb0)
                    + ((long)g * 96 + w * 16 + j) * 96 + kt * 32 + hi * 8;
                const float4 va = *(const float4*)src;
                const float4 vb = *(const float4*)(src + 4);
                f16x8 t = { (_Float16)va.x, (_Float16)va.y, (_Float16)va.z, (_Float16)va.w,
                            (_Float16)vb.x, (_Float16)vb.y, (_Float16)vb.z, (_Float16)vb.w };
                wf[m][g][kt] = t;
            }
    f32x4 bias[2][3];
    #pragma unroll
    for (int m = 0; m < 2; m++)
        #pragma unroll
        for (int g = 0; g < 3; g++) {
            const float* bsrc = (m ? bhh : bih) + (long)r * G3 + g * 96 + w * 16 + hi * 4;
            f32x4 t = { bsrc[0], bsrc[1], bsrc[2], bsrc[3] };
            bias[m][g] = t;
        }

    const bool owns = (j < 12);
    const int  bb   = (j < 12) ? j / 3 : 0;
    const int  hb   = (j < 12) ? j % 3 : 0;
    float* ioptr = io + ((((long)bb * ROI + r) * T_) * H_ + hb) * 96 + k0;
    const f32x4 zero4 = { 0.f, 0.f, 0.f, 0.f };

    // ---- prologue: first input batch, stage x0/x1, zero h[-1] ----
    f32x4 cur[TB], nxt[TB];
    #pragma unroll
    for (int jj = 0; jj < TB; jj++)
        cur[jj] = owns ? *(const f32x4*)(ioptr + jj * (H_ * 96)) : zero4;

    {
        f16x4 z4 = { (_Float16)0.f, (_Float16)0.f, (_Float16)0.f, (_Float16)0.f };
        *(f16x4*)&hact[1][j][k0] = z4;                      // h[-1] = 0
        f16x4 x0 = { (_Float16)cur[0][0], (_Float16)cur[0][1],
                     (_Float16)cur[0][2], (_Float16)cur[0][3] };
        f16x4 x1 = { (_Float16)cur[1][0], (_Float16)cur[1][1],
                     (_Float16)cur[1][2], (_Float16)cur[1][3] };
        *(f16x4*)&xact[0][j][k0] = x0;                      // x[0]
        *(f16x4*)&xact[1][j][k0] = x1;                      // x[1]
    }
    float hprev[4] = { 0.f, 0.f, 0.f, 0.f };
    BAR();   // B0

    // ---- xpre(0) into xpa ----
    f32x4 xpa[3], xpb[3];
    #pragma unroll
    for (int g = 0; g < 3; g++) xpa[g] = bias[0][g];
    #pragma unroll
    for (int kt = 0; kt < 3; kt++) {
        const f16x8 bx = *(const f16x8*)&xact[0][j][kt * 32 + hi * 8];
        #pragma unroll
        for (int g = 0; g < 3; g++)
            xpa[g] = __builtin_amdgcn_mfma_f32_16x16x32_f16(wf[0][g][kt], bx, xpa[g], 0, 0, 0);
    }

    // XC: xpre(t) regs; XN: xpre(t+1) dest; RB/WB: hact read/write parity;
    // XRB/XWB: xact read (x[t+1]) / write (x[t+2]) parity; XNEXTV: x[t+2].
#define GRU_STEP(XC, XN, RB, WB, XRB, XWB, XNEXTV, TGLOB)                        \
    {                                                                            \
        /* x-side: xpre(t+1) — independent of the recurrence chain */            \
        _Pragma("unroll")                                                        \
        for (int g = 0; g < 3; g++) XN[g] = bias[0][g];                          \
        _Pragma("unroll")                                                        \
        for (int kt = 0; kt < 3; kt++) {                                         \
            const f16x8 bx = *(const f16x8*)&xact[XRB][j][kt * 32 + hi * 8];     \
            _Pragma("unroll")                                                    \
            for (int g = 0; g < 3; g++)                                          \
                XN[g] = __builtin_amdgcn_mfma_f32_16x16x32_f16(wf[0][g][kt], bx, XN[g], 0, 0, 0); \
        }                                                                        \
        /* h-side: the critical chain */                                         \
        f32x4 d0 = bias[1][0], d1 = bias[1][1], d2 = bias[1][2];                 \
        _Pragma("unroll")                                                        \
        for (int kt = 0; kt < 3; kt++) {                                         \
            const f16x8 bh = *(const f16x8*)&hact[RB][j][kt * 32 + hi * 8];      \
            d0 = __builtin_amdgcn_mfma_f32_16x16x32_f16(wf[1][0][kt], bh, d0, 0, 0, 0); \
            d1 = __builtin_amdgcn_mfma_f32_16x16x32_f16(wf[1][1][kt], bh, d1, 0, 0, 0); \
            d2 = __builtin_amdgcn_mfma_f32_16x16x32_f16(wf[1][2][kt], bh, d2, 0, 0, 0); \
        }                                                                        \
        f16x4 hq; f32x4 ov;                                                      \
        _Pragma("unroll")                                                        \
        for (int q = 0; q < 4; q++) {                                            \
            const float xr = XC[0][q], xz = XC[1][q], xn = XC[2][q];             \
            const float hr = d0[q], hz = d1[q], hn = d2[q];                      \
            const float rg = 1.f / (1.f + __expf(-(xr + hr)));                   \
            const float zg = 1.f / (1.f + __expf(-(xz + hz)));                   \
            const float pre = xn + rg * hn;                                      \
            const float ng = 1.f - 2.f / (__expf(2.f * pre) + 1.f);              \
            const float hnew = (1.f - zg) * ng + zg * hprev[q];                  \
            hprev[q] = hnew; ov[q] = hnew; hq[q] = (_Float16)hnew;               \
        }                                                                        \
        *(f16x4*)&hact[WB][j][k0] = hq;                                          \
        {                                                                        \
            const f32x4 xv = (XNEXTV);                                           \
            f16x4 xq = { (_Float16)xv[0], (_Float16)xv[1],                       \
                         (_Float16)xv[2], (_Float16)xv[3] };                     \
            *(f16x4*)&xact[XWB][j][k0] = xq;                                     \
        }                                                                        \
        if (owns) *(f32x4*)(ioptr + (TGLOB) * (H_ * 96)) = ov;                   \
        BAR();                                                                   \
    }

    for (int tt = 0; tt < T_ / TB; tt++) {
        // prefetch next batch (stays in flight across raw barriers; first
        // use is jj=2's staging, ~2 steps of latency hiding)
        if (tt + 1 < T_ / TB) {
            #pragma unroll
            for (int p = 0; p < TB; p++)
                nxt[p] = owns ? *(const f32x4*)(ioptr + ((tt + 1) * TB + p) * (H_ * 96))
                              : zero4;
        } else {
            #pragma unroll
            for (int p = 0; p < TB; p++) nxt[p] = zero4;
        }
        const int t0 = tt * TB;
        GRU_STEP(xpa, xpb, 1, 0, 1, 0, cur[2], t0 + 0)   // t even
        GRU_STEP(xpb, xpa, 0, 1, 0, 1, cur[3], t0 + 1)   // t odd
        GRU_STEP(xpa, xpb, 1, 0, 1, 0, nxt[0], t0 + 2)   // t even
        GRU_STEP(xpb, xpa, 0, 1, 0, 1, nxt[1], t0 + 3)   // t odd
        #pragma unroll
        for (int p = 0; p < TB; p++) cur[p] = nxt[p];
    }
#undef GRU_STEP
}

extern "C" void kernel_launch(void* const* d_in, const int* in_sizes, int n_in,
                              void* d_out, int out_size, void* d_ws, size_t ws_size,
                              hipStream_t stream) {
    (void)in_sizes; (void)n_in; (void)out_size; (void)d_ws; (void)ws_size;
    const float* x   = (const float*)d_in[0];
    const float* a   = (const float*)d_in[1];
    const float* eps = (const float*)d_in[2];
    const float* W1  = (const float*)d_in[3];
    const float* b1  = (const float*)d_in[4];
    const float* g1  = (const float*)d_in[5];
    const float* be1 = (const float*)d_in[6];
    const float* W2  = (const float*)d_in[7];
    const float* b2  = (const float*)d_in[8];
    const float* g2  = (const float*)d_in[9];
    const float* be2 = (const float*)d_in[10];
    const float* Wih = (const float*)d_in[11];
    const float* Whh = (const float*)d_in[12];
    const float* bih = (const float*)d_in[13];
    const float* bhh = (const float*)d_in[14];
    float* out = (float*)d_out;

    stageA<<<B_ * T_ * H_, 384, SMEM_A, stream>>>(x, a, eps, W1, b1, g1, be1,
                                                  W2, b2, g2, be2, out);
    stageC<<<ROI, 384, 0, stream>>>(Wih, Whh, bih, bhh, out);
}